// Round 5
// baseline (9882.513 us; speedup 1.0000x reference)
//
#include <hip/hip_runtime.h>
#include <hip/hip_bf16.h>

#define L_ 2
#define H_ 1024
#define Z_ 256
#define B_ 128
#define SRC_ 64
#define K_ 48
#define BH_ (B_ * H_)
#define BZ_ (B_ * Z_)
#define BKZ_ ((size_t)B_ * K_ * Z_)
#define KA_ 2304   // lstm0 GEMM K: z(256) | attn(1024) | h0(1024)
#define KB_ 2048   // lstm1 GEMM K: h0n(1024) | h1(1024)

typedef unsigned short u16;
typedef __attribute__((ext_vector_type(8))) short short8;
typedef __attribute__((ext_vector_type(4))) float f32x4;

// ---------------- static device workspace ----------------
__device__ u16 g_Wc0[4096 * KA_];     // lstm0 weights, gate-interleaved rows [4h+g][KA]
__device__ u16 g_Wc1[4096 * KB_];     // lstm1 weights
__device__ u16 g_Wmq[512 * 1024];     // mu/sigma rows interleaved [2z+sel][1024]
__device__ u16 g_Woutb[1024 * 2048];  // Wout bf16
__device__ u16 g_WinT[1024 * 1024];   // Win transposed bf16
__device__ u16 g_ctxb[8192 * 1024];   // context bf16 [B*SRC][H]
__device__ u16 g_ctxW[8192 * 1024];   // ctx @ Wout[:, :H]^T
__device__ u16 g_ctxWin[8192 * 1024]; // ctx @ Win
__device__ u16 g_XA[2][B_ * KA_];     // lstm0 input (dbl-buffered): z|attn|h0state
__device__ u16 g_XB[2][B_ * KB_];     // lstm1 input: h0n|h1state
__device__ u16 g_XC[B_ * H_];         // h1n unfrozen (query / musig input)
__device__ float g_pb0[4096], g_pb1[4096], g_pbmq[512], g_wk0[4096];
__device__ float g_cs0[BH_], g_cs1[BH_], g_align[B_ * SRC_];
__device__ unsigned g_barrier;

__device__ __forceinline__ float sigm(float x) { return 1.0f / (1.0f + expf(-x)); }
__device__ __forceinline__ u16 f2b(float f) {
    union { float f; unsigned u; } x; x.f = f;
    unsigned r = x.u + 0x7fffu + ((x.u >> 16) & 1u);
    return (u16)(r >> 16);
}
__device__ __forceinline__ float b2f(u16 s) {
    union { unsigned u; float f; } x; x.u = ((unsigned)s) << 16;
    return x.f;
}

// ---------------- grid barrier (monotonic, 256 blocks co-resident) ----------------
__device__ __forceinline__ void gsync(unsigned& cnt) {
    __syncthreads();
    if (threadIdx.x == 0) {
        __threadfence();
        atomicAdd(&g_barrier, 1u);
        cnt += 256;
        while (__hip_atomic_load(&g_barrier, __ATOMIC_RELAXED, __HIP_MEMORY_SCOPE_AGENT) < cnt)
            __builtin_amdgcn_s_sleep(1);
        __threadfence();
    }
    __syncthreads();
}

// ---------------- prep kernels ----------------
__global__ void prep_wc0(const float* __restrict__ Wih, const float* __restrict__ Whh,
                         const float* __restrict__ bih, const float* __restrict__ bhh) {
    int n = blockIdx.x;                 // interleaved row: n = 4h+g
    int h = n >> 2, g = n & 3, r = g * 1024 + h;
    u16* row = g_Wc0 + (size_t)n * KA_;
    for (int j = threadIdx.x; j < KA_; j += 256) {
        float v = (j < 256) ? Wih[(size_t)r * 1281 + j]
                : (j < 1280) ? Wih[(size_t)r * 1281 + j + 1]
                             : Whh[(size_t)r * 1024 + (j - 1280)];
        row[j] = f2b(v);
    }
    if (threadIdx.x == 0) {
        g_wk0[n] = Wih[(size_t)r * 1281 + 256];
        g_pb0[n] = bih[r] + bhh[r];
    }
}

__global__ void prep_wc1(const float* __restrict__ Wih, const float* __restrict__ Whh,
                         const float* __restrict__ bih, const float* __restrict__ bhh) {
    int n = blockIdx.x;
    int h = n >> 2, g = n & 3, r = g * 1024 + h;
    u16* row = g_Wc1 + (size_t)n * KB_;
    for (int j = threadIdx.x; j < KB_; j += 256) {
        float v = (j < 1024) ? Wih[(size_t)r * 1024 + j] : Whh[(size_t)r * 1024 + (j - 1024)];
        row[j] = f2b(v);
    }
    if (threadIdx.x == 0) g_pb1[n] = bih[r] + bhh[r];
}

__global__ void prep_wmq(const float* __restrict__ muW, const float* __restrict__ mub,
                         const float* __restrict__ sgW, const float* __restrict__ sgb) {
    int n = blockIdx.x;                 // n = 2z+sel
    int z = n >> 1, sel = n & 1;
    const float* src = sel ? sgW : muW;
    u16* row = g_Wmq + (size_t)n * 1024;
    for (int j = threadIdx.x; j < 1024; j += 256) row[j] = f2b(src[(size_t)z * 1024 + j]);
    if (threadIdx.x == 0) g_pbmq[n] = sel ? sgb[z] : mub[z];
}

__global__ void prep_copy(const float* __restrict__ in, u16* __restrict__ out, int n) {
    for (int i = blockIdx.x * 256 + threadIdx.x; i < n; i += gridDim.x * 256)
        out[i] = f2b(in[i]);
}

__global__ void prep_winT(const float* __restrict__ Win) {
    __shared__ float t[32][33];
    int bx = blockIdx.x * 32, by = blockIdx.y * 32;
    int tx = threadIdx.x & 31, ty0 = threadIdx.x >> 5;
    for (int it = 0; it < 4; ++it) {
        int ty = ty0 + it * 8;
        t[ty][tx] = Win[(size_t)(by + ty) * 1024 + bx + tx];
    }
    __syncthreads();
    for (int it = 0; it < 4; ++it) {
        int ty = ty0 + it * 8;
        g_WinT[(size_t)(bx + ty) * 1024 + by + tx] = f2b(t[tx][ty]);
    }
}

// ---------------- generic MFMA K-loop (2 m-frags x 1 n-frag) ----------------
template <int K>
__device__ __forceinline__ void mm_loop(const u16* __restrict__ A, int sA,
                                        const u16* __restrict__ W, int sW,
                                        int n0, int mbase, int lane,
                                        f32x4& acc0, f32x4& acc1) {
    const int quad = lane >> 4, l16 = lane & 15;
    const u16* pa0 = A + (size_t)(mbase + l16) * sA + quad * 8;
    const u16* pa1 = pa0 + (size_t)16 * sA;
    const u16* pw = W + (size_t)(n0 + l16) * sW + quad * 8;
#pragma unroll 4
    for (int k0 = 0; k0 < K; k0 += 32) {
        short8 a0 = *(const short8*)(const void*)(pa0 + k0);
        short8 a1 = *(const short8*)(const void*)(pa1 + k0);
        short8 b = *(const short8*)(const void*)(pw + k0);
        acc0 = __builtin_amdgcn_mfma_f32_16x16x32_bf16(a0, b, acc0, 0, 0, 0);
        acc1 = __builtin_amdgcn_mfma_f32_16x16x32_bf16(a1, b, acc1, 0, 0, 0);
    }
}

// stage C into sm[64][33]; wave covers local rows wm*32..+32, cols wn*16..+16
__device__ __forceinline__ void stage_C(float* sm, int wm, int wn, int lane,
                                        const f32x4& acc0, const f32x4& acc1) {
    int quad = lane >> 4, l16 = lane & 15;
    int m0 = wm * 32 + quad * 4, c = wn * 16 + l16;
#pragma unroll
    for (int r = 0; r < 4; ++r) {
        sm[(m0 + r) * 33 + c] = acc0[r];
        sm[(m0 + 16 + r) * 33 + c] = acc1[r];
    }
}

// ---------------- persistent-loop phases ----------------
// lstm phase: 256 blocks, tile Mt=64 (mhalf) x Nt=32
template <int LAYER>
__device__ void phase_lstm(float* sm, const int* __restrict__ kvec, int step) {
    constexpr int K = (LAYER == 0) ? KA_ : KB_;
    const int p = step & 1;
    const u16* A = (LAYER == 0) ? g_XA[p] : g_XB[p];
    const u16* W = (LAYER == 0) ? g_Wc0 : g_Wc1;
    const float* pb = (LAYER == 0) ? g_pb0 : g_pb1;
    float* cs = (LAYER == 0) ? g_cs0 : g_cs1;
    const u16* stOld = (LAYER == 0) ? (g_XA[p] + 1280) : (g_XB[p] + 1024);
    u16* stNew = (LAYER == 0) ? (g_XA[1 - p] + 1280) : (g_XB[1 - p] + 1024);
    const int stStride = (LAYER == 0) ? KA_ : KB_;
    u16* hout = (LAYER == 0) ? g_XB[p] : g_XC;
    const int hoStride = (LAYER == 0) ? KB_ : 1024;

    const int tid = threadIdx.x, w = tid >> 6, lane = tid & 63;
    const int wm = w >> 1, wn = w & 1;
    const int mhalf = blockIdx.x >> 7, n0 = (blockIdx.x & 127) * 32;

    f32x4 acc0 = {0.f, 0.f, 0.f, 0.f}, acc1 = {0.f, 0.f, 0.f, 0.f};
    mm_loop<K>(A, K, W, K, n0 + wn * 16, mhalf * 64 + wm * 32, lane, acc0, acc1);
    stage_C(sm, wm, wn, lane, acc0, acc1);
    __syncthreads();

#pragma unroll
    for (int it = 0; it < 2; ++it) {
        int u = tid + it * 256;             // 0..511
        int bl = u & 63, hl = u >> 6;       // hl 0..7
        int b = mhalf * 64 + bl;
        float gi = sm[bl * 33 + 4 * hl + 0] + pb[n0 + 4 * hl + 0];
        float gf = sm[bl * 33 + 4 * hl + 1] + pb[n0 + 4 * hl + 1];
        float gg = sm[bl * 33 + 4 * hl + 2] + pb[n0 + 4 * hl + 2];
        float go = sm[bl * 33 + 4 * hl + 3] + pb[n0 + 4 * hl + 3];
        if (LAYER == 0) {
            float kf = (float)kvec[b];
            gi += kf * g_wk0[n0 + 4 * hl + 0];
            gf += kf * g_wk0[n0 + 4 * hl + 1];
            gg += kf * g_wk0[n0 + 4 * hl + 2];
            go += kf * g_wk0[n0 + 4 * hl + 3];
        }
        int hg = (n0 >> 2) + hl;
        float cold = cs[b * 1024 + hg];
        float cn = sigm(gf) * cold + sigm(gi) * tanhf(gg);
        float hn = sigm(go) * tanhf(cn);
        hout[(size_t)b * hoStride + hg] = f2b(hn);   // unfrozen output
        if (step < kvec[b]) {
            stNew[(size_t)b * stStride + hg] = f2b(hn);
            cs[b * 1024 + hg] = cn;
        } else {
            stNew[(size_t)b * stStride + hg] = stOld[(size_t)b * stStride + hg];
        }
    }
}

// musig (blocks 0..31) + scores/softmax (blocks 32..159)
__device__ void phase_mq(float* sm, const float* __restrict__ eps,
                         const int* __restrict__ kvec, float* __restrict__ out,
                         int step, bool do_mu, bool do_sc) {
    const int tid = threadIdx.x;
    if (blockIdx.x < 32) {
        if (!do_mu) return;
        const int w = tid >> 6, lane = tid & 63, wm = w >> 1, wn = w & 1;
        const int mhalf = blockIdx.x >> 4, n0 = (blockIdx.x & 15) * 32;
        f32x4 acc0 = {0.f, 0.f, 0.f, 0.f}, acc1 = {0.f, 0.f, 0.f, 0.f};
        mm_loop<1024>(g_XC, 1024, g_Wmq, 1024, n0 + wn * 16, mhalf * 64 + wm * 32,
                      lane, acc0, acc1);
        stage_C(sm, wm, wn, lane, acc0, acc1);
        __syncthreads();
        u16* zdst = g_XA[(step + 1) & 1];
        float* out_z = out;
        float* out_mu = out + BKZ_;
        float* out_sg = out + 2 * BKZ_;
#pragma unroll
        for (int it = 0; it < 4; ++it) {
            int u = tid + it * 256;         // 0..1023
            int bl = u & 63, zl = u >> 6;   // zl 0..15
            int b = mhalf * 64 + bl;
            float mu = sm[bl * 33 + 2 * zl] + g_pbmq[n0 + 2 * zl];
            float sg = sm[bl * 33 + 2 * zl + 1] + g_pbmq[n0 + 2 * zl + 1];
            int zg = (n0 >> 1) + zl;
            float e = eps[((size_t)step * B_ + b) * Z_ + zg];
            float zn = mu + expf(sg) * e;
            zdst[(size_t)b * KA_ + zg] = f2b(zn);
            bool valid = step < kvec[b];
            size_t o = ((size_t)b * K_ + step) * Z_ + zg;
            out_z[o] = valid ? zn : 0.f;
            out_mu[o] = valid ? mu : 0.f;
            out_sg[o] = valid ? sg : 0.f;
        }
    } else if (blockIdx.x < 160) {
        if (!do_sc) return;
        const int b = blockIdx.x - 32;
        float* qf = sm;                     // [1024]
        float* parts = sm + 1024;           // [64][4]
        for (int i = tid; i < 1024; i += 256) qf[i] = b2f(g_XC[b * 1024 + i]);
        __syncthreads();
        int s = tid >> 2, part = tid & 3;
        const u16* row = g_ctxWin + ((size_t)(b * SRC_ + s)) * 1024 + part * 256;
        float pacc = 0.f;
        for (int j = 0; j < 256; j += 8) {
            short8 v = *(const short8*)(const void*)(row + j);
#pragma unroll
            for (int t = 0; t < 8; ++t) pacc += qf[part * 256 + j + t] * b2f(((u16*)&v)[t]);
        }
        parts[s * 4 + part] = pacc;
        __syncthreads();
        if (tid < 64) {
            float v = parts[tid * 4] + parts[tid * 4 + 1] + parts[tid * 4 + 2] + parts[tid * 4 + 3];
            float mx = v;
            for (int o = 32; o; o >>= 1) mx = fmaxf(mx, __shfl_xor(mx, o, 64));
            float e = expf(v - mx), sum = e;
            for (int o = 32; o; o >>= 1) sum += __shfl_xor(sum, o, 64);
            g_align[b * SRC_ + tid] = e / sum;
        }
    }
}

// attn: blocks 0..63, q-GEMM (N=1024) + align contraction; writes XA[dp] attn region
__device__ void phase_attn(float* sm, int dp) {
    if (blockIdx.x >= 64) return;
    const int tid = threadIdx.x, w = tid >> 6, lane = tid & 63, wm = w >> 1, wn = w & 1;
    const int mhalf = blockIdx.x >> 5, n0 = (blockIdx.x & 31) * 32;
    f32x4 acc0 = {0.f, 0.f, 0.f, 0.f}, acc1 = {0.f, 0.f, 0.f, 0.f};
    mm_loop<1024>(g_XC, 1024, g_Woutb + 1024, 2048, n0 + wn * 16, mhalf * 64 + wm * 32,
                  lane, acc0, acc1);
    stage_C(sm, wm, wn, lane, acc0, acc1);
    __syncthreads();
    int bl = tid >> 2, cg = tid & 3;        // 64 b x 4 col-groups of 8
    int b = mhalf * 64 + bl;
    const u16* base = g_ctxW + (size_t)b * SRC_ * 1024 + n0 + cg * 8;
    float a8[8] = {0.f, 0.f, 0.f, 0.f, 0.f, 0.f, 0.f, 0.f};
    for (int s = 0; s < SRC_; ++s) {
        float al = g_align[b * SRC_ + s];
        short8 v = *(const short8*)(const void*)(base + (size_t)s * 1024);
#pragma unroll
        for (int j = 0; j < 8; ++j) a8[j] += al * b2f(((u16*)&v)[j]);
    }
    u16 ov[8];
#pragma unroll
    for (int j = 0; j < 8; ++j) ov[j] = f2b(tanhf(a8[j] + sm[bl * 33 + cg * 8 + j]));
    *(short8*)(void*)(g_XA[dp] + (size_t)b * KA_ + 256 + n0 + cg * 8) = *(short8*)(void*)ov;
}

// ---------------- the persistent 48-step loop ----------------
__global__ __launch_bounds__(256, 1) void k_loop(const float* __restrict__ eps,
                                                 const int* __restrict__ kvec,
                                                 float* __restrict__ out) {
    __shared__ float sm[64 * 33];
    unsigned cnt = 0;
    // initial attention with q = c0[-1] (preset in g_XC by k_init)
    phase_mq(sm, eps, kvec, out, 0, false, true);
    gsync(cnt);
    phase_attn(sm, 0);
    gsync(cnt);
    for (int i = 0; i < K_; ++i) {
        phase_lstm<0>(sm, kvec, i); gsync(cnt);
        phase_lstm<1>(sm, kvec, i); gsync(cnt);
        phase_mq(sm, eps, kvec, out, i, true, i + 1 < K_); gsync(cnt);
        if (i + 1 < K_) { phase_attn(sm, (i + 1) & 1); gsync(cnt); }
    }
}

// ---------------- init / final ----------------
__global__ void k_init(const float* __restrict__ h0, const float* __restrict__ c0,
                       const float* __restrict__ z0) {
    int i = blockIdx.x * 256 + threadIdx.x;  // i < BH_
    if (i == 0) g_barrier = 0;
    int b = i >> 10, h = i & 1023;
    g_XA[0][(size_t)b * KA_ + 1280 + h] = f2b(h0[i]);            // h0 layer0 state
    g_XB[0][(size_t)b * KB_ + 1024 + h] = f2b(h0[BH_ + i]);      // h layer1 state
    g_XC[i] = f2b(c0[BH_ + i]);                                  // initial query c0[-1]
    g_cs0[i] = c0[i];
    g_cs1[i] = c0[BH_ + i];
    if (i < BZ_) {
        int bb = i >> 8, z = i & 255;
        g_XA[0][(size_t)bb * KA_ + z] = f2b(z0[i]);
    }
}

__global__ void k_final(float* __restrict__ out) {
    int i = blockIdx.x * 256 + threadIdx.x;  // i < BH_
    int b = i >> 10, h = i & 1023;
    float* hf = out + (size_t)3 * BKZ_;
    float* cf = hf + 2 * BH_;
    hf[i] = b2f(g_XA[0][(size_t)b * KA_ + 1280 + h]);
    hf[BH_ + i] = b2f(g_XB[0][(size_t)b * KB_ + 1024 + h]);
    cf[i] = g_cs0[i];
    cf[BH_ + i] = g_cs1[i];
}

// ---------------- prep GEMM: Out[m][n] = sum_k A[m][k]*W[n][k], 128x64 tiles ----------------
__global__ __launch_bounds__(256) void k_gemm_prep(const u16* __restrict__ A, int sA,
                                                   const u16* __restrict__ W, int sW,
                                                   u16* __restrict__ Out, int sO) {
    const int tid = threadIdx.x, w = tid >> 6, lane = tid & 63;
    const int quad = lane >> 4, l16 = lane & 15;
    const int n0 = blockIdx.x * 64;
    const int mb = blockIdx.y * 128 + w * 32;
    f32x4 acc[2][4] = {};
    const u16* pa0 = A + (size_t)(mb + l16) * sA + quad * 8;
    const u16* pa1 = pa0 + (size_t)16 * sA;
    const u16* pw = W + (size_t)(n0 + l16) * sW + quad * 8;
#pragma unroll 2
    for (int k0 = 0; k0 < 1024; k0 += 32) {
        short8 a0 = *(const short8*)(const void*)(pa0 + k0);
        short8 a1 = *(const short8*)(const void*)(pa1 + k0);
#pragma unroll
        for (int j = 0; j < 4; ++j) {
            short8 b = *(const short8*)(const void*)(pw + (size_t)j * 16 * sW + k0);
            acc[0][j] = __builtin_amdgcn_mfma_f32_16x16x32_bf16(a0, b, acc[0][j], 0, 0, 0);
            acc[1][j] = __builtin_amdgcn_mfma_f32_16x16x32_bf16(a1, b, acc[1][j], 0, 0, 0);
        }
    }
#pragma unroll
    for (int i = 0; i < 2; ++i)
#pragma unroll
        for (int j = 0; j < 4; ++j)
#pragma unroll
            for (int r = 0; r < 4; ++r)
                Out[(size_t)(mb + i * 16 + quad * 4 + r) * sO + n0 + j * 16 + l16] =
                    f2b(acc[i][j][r]);
}

extern "C" void kernel_launch(void* const* d_in, const int* in_sizes, int n_in,
                              void* d_out, int out_size, void* d_ws, size_t ws_size,
                              hipStream_t stream) {
    (void)in_sizes; (void)n_in; (void)out_size; (void)d_ws; (void)ws_size;
    const float* h0 = (const float*)d_in[0];
    const float* c0 = (const float*)d_in[1];
    const float* ctx = (const float*)d_in[2];
    const float* z0 = (const float*)d_in[3];
    const int* kvec = (const int*)d_in[4];
    const float* eps = (const float*)d_in[5];
    const float* Wih0 = (const float*)d_in[6];
    const float* Whh0 = (const float*)d_in[7];
    const float* bih0 = (const float*)d_in[8];
    const float* bhh0 = (const float*)d_in[9];
    const float* Wih1 = (const float*)d_in[10];
    const float* Whh1 = (const float*)d_in[11];
    const float* bih1 = (const float*)d_in[12];
    const float* bhh1 = (const float*)d_in[13];
    const float* Win = (const float*)d_in[14];
    const float* Wout = (const float*)d_in[15];
    const float* muW = (const float*)d_in[16];
    const float* mub = (const float*)d_in[17];
    const float* sgW = (const float*)d_in[18];
    const float* sgb = (const float*)d_in[19];
    float* out = (float*)d_out;

    dim3 blk(256);
    // ---- one-time prep ----
    prep_wc0<<<4096, blk, 0, stream>>>(Wih0, Whh0, bih0, bhh0);
    prep_wc1<<<4096, blk, 0, stream>>>(Wih1, Whh1, bih1, bhh1);
    prep_wmq<<<512, blk, 0, stream>>>(muW, mub, sgW, sgb);
    {
        u16* woutb; hipGetSymbolAddress((void**)&woutb, HIP_SYMBOL(g_Woutb));
        u16* ctxb; hipGetSymbolAddress((void**)&ctxb, HIP_SYMBOL(g_ctxb));
        u16* winT; hipGetSymbolAddress((void**)&winT, HIP_SYMBOL(g_WinT));
        u16* ctxW; hipGetSymbolAddress((void**)&ctxW, HIP_SYMBOL(g_ctxW));
        u16* ctxWin; hipGetSymbolAddress((void**)&ctxWin, HIP_SYMBOL(g_ctxWin));
        prep_copy<<<2048, blk, 0, stream>>>(Wout, woutb, 1024 * 2048);
        prep_copy<<<8192, blk, 0, stream>>>(ctx, ctxb, 8192 * 1024);
        prep_winT<<<dim3(32, 32), blk, 0, stream>>>(Win);
        // ctxW = ctx @ Wout[:, :1024]^T ; ctxWin = ctx @ Win
        k_gemm_prep<<<dim3(16, 64), blk, 0, stream>>>(ctxb, 1024, woutb, 2048, ctxW, 1024);
        k_gemm_prep<<<dim3(16, 64), blk, 0, stream>>>(ctxb, 1024, winT, 1024, ctxWin, 1024);
    }
    // ---- init state, then the persistent 48-step loop ----
    k_init<<<BH_ / 256, blk, 0, stream>>>(h0, c0, z0);
    k_loop<<<256, blk, 0, stream>>>(eps, kvec, out);
    // K_=48 even -> final states in parity-0 buffers
    k_final<<<BH_ / 256, blk, 0, stream>>>(out);
}

// Round 6
// 5142.531 us; speedup vs baseline: 1.9217x; 1.9217x over previous
//
#include <hip/hip_runtime.h>
#include <hip/hip_bf16.h>

#define L_ 2
#define H_ 1024
#define Z_ 256
#define B_ 128
#define SRC_ 64
#define K_ 48
#define BH_ (B_ * H_)
#define BZ_ (B_ * Z_)
#define BKZ_ ((size_t)B_ * K_ * Z_)
#define KA_ 2304   // lstm0 GEMM K: z(256) | attn(1024) | h0(1024)
#define KB_ 2048   // lstm1 GEMM K: h0n(1024) | h1(1024)

typedef unsigned short u16;
typedef __attribute__((ext_vector_type(8))) short short8;
typedef __attribute__((ext_vector_type(4))) float f32x4;

// ---------------- static device workspace ----------------
__device__ __align__(16) u16 g_Wc0[4096 * KA_];     // lstm0 weights [4h+g][KA]
__device__ __align__(16) u16 g_Wc1[4096 * KB_];     // lstm1 weights
__device__ __align__(16) u16 g_Wmq[512 * 1024];     // mu/sigma rows interleaved [2z+sel][1024]
__device__ __align__(16) u16 g_Woutb[1024 * 2048];  // Wout bf16
__device__ __align__(16) u16 g_WinT[1024 * 1024];   // Win transposed bf16
__device__ __align__(16) u16 g_ctxb[8192 * 1024];   // context bf16 [B*SRC][H]
__device__ __align__(16) u16 g_ctxW[8192 * 1024];   // ctx @ Wout[:, :H]^T
__device__ __align__(16) u16 g_ctxWin[8192 * 1024]; // ctx @ Win
__device__ __align__(16) u16 g_XA[2][B_ * KA_];     // lstm0 input (dbl-buf): z|attn|h0state
__device__ __align__(16) u16 g_XB[2][B_ * KB_];     // lstm1 input: h0n|h1state
__device__ __align__(16) u16 g_XC[B_ * H_];         // h1n unfrozen (query / musig input)
__device__ float g_pb0[4096], g_pb1[4096], g_pbmq[512], g_wk0[4096];
__device__ float g_cs0[BH_], g_cs1[BH_], g_align[B_ * SRC_];

__device__ __forceinline__ float sigm(float x) { return 1.0f / (1.0f + expf(-x)); }
__device__ __forceinline__ u16 f2b(float f) {
    union { float f; unsigned u; } x; x.f = f;
    unsigned r = x.u + 0x7fffu + ((x.u >> 16) & 1u);
    return (u16)(r >> 16);
}
__device__ __forceinline__ float b2f(u16 s) {
    union { unsigned u; float f; } x; x.u = ((unsigned)s) << 16;
    return x.f;
}

// ---------------- prep kernels ----------------
__global__ void prep_wc0(const float* __restrict__ Wih, const float* __restrict__ Whh,
                         const float* __restrict__ bih, const float* __restrict__ bhh) {
    int n = blockIdx.x;                 // interleaved row: n = 4h+g
    int h = n >> 2, g = n & 3, r = g * 1024 + h;
    u16* row = g_Wc0 + (size_t)n * KA_;
    for (int j = threadIdx.x; j < KA_; j += 256) {
        float v = (j < 256) ? Wih[(size_t)r * 1281 + j]
                : (j < 1280) ? Wih[(size_t)r * 1281 + j + 1]
                             : Whh[(size_t)r * 1024 + (j - 1280)];
        row[j] = f2b(v);
    }
    if (threadIdx.x == 0) {
        g_wk0[n] = Wih[(size_t)r * 1281 + 256];
        g_pb0[n] = bih[r] + bhh[r];
    }
}

__global__ void prep_wc1(const float* __restrict__ Wih, const float* __restrict__ Whh,
                         const float* __restrict__ bih, const float* __restrict__ bhh) {
    int n = blockIdx.x;
    int h = n >> 2, g = n & 3, r = g * 1024 + h;
    u16* row = g_Wc1 + (size_t)n * KB_;
    for (int j = threadIdx.x; j < KB_; j += 256) {
        float v = (j < 1024) ? Wih[(size_t)r * 1024 + j] : Whh[(size_t)r * 1024 + (j - 1024)];
        row[j] = f2b(v);
    }
    if (threadIdx.x == 0) g_pb1[n] = bih[r] + bhh[r];
}

__global__ void prep_wmq(const float* __restrict__ muW, const float* __restrict__ mub,
                         const float* __restrict__ sgW, const float* __restrict__ sgb) {
    int n = blockIdx.x;                 // n = 2z+sel
    int z = n >> 1, sel = n & 1;
    const float* src = sel ? sgW : muW;
    u16* row = g_Wmq + (size_t)n * 1024;
    for (int j = threadIdx.x; j < 1024; j += 256) row[j] = f2b(src[(size_t)z * 1024 + j]);
    if (threadIdx.x == 0) g_pbmq[n] = sel ? sgb[z] : mub[z];
}

__global__ void prep_copy(const float* __restrict__ in, u16* __restrict__ out, int n) {
    for (int i = blockIdx.x * 256 + threadIdx.x; i < n; i += gridDim.x * 256)
        out[i] = f2b(in[i]);
}

__global__ void prep_winT(const float* __restrict__ Win) {
    __shared__ float t[32][33];
    int bx = blockIdx.x * 32, by = blockIdx.y * 32;
    int tx = threadIdx.x & 31, ty0 = threadIdx.x >> 5;
    for (int it = 0; it < 4; ++it) {
        int ty = ty0 + it * 8;
        t[ty][tx] = Win[(size_t)(by + ty) * 1024 + bx + tx];
    }
    __syncthreads();
    for (int it = 0; it < 4; ++it) {
        int ty = ty0 + it * 8;
        g_WinT[(size_t)(bx + ty) * 1024 + by + tx] = f2b(t[tx][ty]);
    }
}

// ---------------- single-fragment MFMA K-loop (1 m-frag x 1 n-frag, deep unroll) ----------
template <int K>
__device__ __forceinline__ void mm1(const u16* __restrict__ A, int sA,
                                    const u16* __restrict__ W, int sW,
                                    int n0, int mbase, int lane, f32x4& acc) {
    const int quad = lane >> 4, l16 = lane & 15;
    const u16* pa = A + (size_t)(mbase + l16) * sA + quad * 8;
    const u16* pw = W + (size_t)(n0 + l16) * sW + quad * 8;
#pragma unroll 8
    for (int k0 = 0; k0 < K; k0 += 32) {
        short8 a = *(const short8*)(const void*)(pa + k0);
        short8 b = *(const short8*)(const void*)(pw + k0);
        acc = __builtin_amdgcn_mfma_f32_16x16x32_bf16(a, b, acc, 0, 0, 0);
    }
}

// stage C into sm[64][17]; wave w covers local rows w*16..w*16+16, cols 0..16
__device__ __forceinline__ void stage_C1(float* sm, int w, int lane, const f32x4& acc) {
    int quad = lane >> 4, l16 = lane & 15;
    int m0 = w * 16 + quad * 4;
#pragma unroll
    for (int r = 0; r < 4; ++r) sm[(m0 + r) * 17 + l16] = acc[r];
}

// ---------------- LSTM GEMM+cell; grid 512 = 8 xcd x (2 mhalf x 32 ntiles) ---------------
template <int LAYER>
__global__ __launch_bounds__(256) void k_lstm_mm(const int* __restrict__ kvec, int step) {
    constexpr int K = (LAYER == 0) ? KA_ : KB_;
    const int p = step & 1;
    const u16* A = (LAYER == 0) ? g_XA[p] : g_XB[p];
    const u16* W = (LAYER == 0) ? g_Wc0 : g_Wc1;
    const float* pb = (LAYER == 0) ? g_pb0 : g_pb1;
    float* cs = (LAYER == 0) ? g_cs0 : g_cs1;
    const u16* stOld = (LAYER == 0) ? (g_XA[p] + 1280) : (g_XB[p] + 1024);
    u16* stNew = (LAYER == 0) ? (g_XA[1 - p] + 1280) : (g_XB[1 - p] + 1024);
    const int stStride = (LAYER == 0) ? KA_ : KB_;
    u16* hout = (LAYER == 0) ? g_XB[p] : g_XC;
    const int hoStride = (LAYER == 0) ? KB_ : 1024;

    const int tid = threadIdx.x, w = tid >> 6, lane = tid & 63;
    const int xcd = blockIdx.x & 7, loc = blockIdx.x >> 3;   // loc 0..63
    const int mhalf = loc & 1;
    const int n0 = (xcd * 32 + (loc >> 1)) * 16;             // XCD owns fixed N-slice

    __shared__ float sm[64 * 17];
    f32x4 acc = {0.f, 0.f, 0.f, 0.f};
    mm1<K>(A, K, W, K, n0, mhalf * 64 + w * 16, lane, acc);
    stage_C1(sm, w, lane, acc);
    __syncthreads();

    // 256 threads = 64 b-rows x 4 h-cols
    int bl = tid & 63, hl = tid >> 6;
    int b = mhalf * 64 + bl;
    float gi = sm[bl * 17 + 4 * hl + 0] + pb[n0 + 4 * hl + 0];
    float gf = sm[bl * 17 + 4 * hl + 1] + pb[n0 + 4 * hl + 1];
    float gg = sm[bl * 17 + 4 * hl + 2] + pb[n0 + 4 * hl + 2];
    float go = sm[bl * 17 + 4 * hl + 3] + pb[n0 + 4 * hl + 3];
    if (LAYER == 0) {
        float kf = (float)kvec[b];
        gi += kf * g_wk0[n0 + 4 * hl + 0];
        gf += kf * g_wk0[n0 + 4 * hl + 1];
        gg += kf * g_wk0[n0 + 4 * hl + 2];
        go += kf * g_wk0[n0 + 4 * hl + 3];
    }
    int hg = (n0 >> 2) + hl;
    float cold = cs[b * 1024 + hg];
    float cn = sigm(gf) * cold + sigm(gi) * tanhf(gg);
    float hn = sigm(go) * tanhf(cn);
    hout[(size_t)b * hoStride + hg] = f2b(hn);   // unfrozen output
    if (step < kvec[b]) {
        stNew[(size_t)b * stStride + hg] = f2b(hn);
        cs[b * 1024 + hg] = cn;
    } else {
        stNew[(size_t)b * stStride + hg] = stOld[(size_t)b * stStride + hg];
    }
}

// ---------------- musig (blocks 0..63) + scores/softmax (blocks 64..191) ----------------
__global__ __launch_bounds__(256) void k_mq(const float* __restrict__ eps,
                                            const int* __restrict__ kvec,
                                            float* __restrict__ out, int step,
                                            int do_mu, int do_sc) {
    __shared__ float sm[1344];
    const int tid = threadIdx.x;
    if (blockIdx.x < 64) {
        if (!do_mu) return;
        const int w = tid >> 6, lane = tid & 63;
        const int xcd = blockIdx.x & 7, loc = blockIdx.x >> 3;   // loc 0..7
        const int mhalf = loc & 1;
        const int n0 = (xcd * 4 + (loc >> 1)) * 16;              // N=512 total
        f32x4 acc = {0.f, 0.f, 0.f, 0.f};
        mm1<1024>(g_XC, 1024, g_Wmq, 1024, n0, mhalf * 64 + w * 16, lane, acc);
        stage_C1(sm, w, lane, acc);
        __syncthreads();
        u16* zdst = g_XA[(step + 1) & 1];
        float* out_z = out;
        float* out_mu = out + BKZ_;
        float* out_sg = out + 2 * BKZ_;
#pragma unroll
        for (int it = 0; it < 2; ++it) {
            int u = tid + it * 256;          // 0..511 = 64 b x 8 z
            int bl = u & 63, zl = u >> 6;
            int b = mhalf * 64 + bl;
            float mu = sm[bl * 17 + 2 * zl] + g_pbmq[n0 + 2 * zl];
            float sg = sm[bl * 17 + 2 * zl + 1] + g_pbmq[n0 + 2 * zl + 1];
            int zg = (n0 >> 1) + zl;
            float e = eps[((size_t)step * B_ + b) * Z_ + zg];
            float zn = mu + expf(sg) * e;
            zdst[(size_t)b * KA_ + zg] = f2b(zn);
            bool valid = step < kvec[b];
            size_t o = ((size_t)b * K_ + step) * Z_ + zg;
            out_z[o] = valid ? zn : 0.f;
            out_mu[o] = valid ? mu : 0.f;
            out_sg[o] = valid ? sg : 0.f;
        }
    } else {
        if (!do_sc) return;
        const int b = blockIdx.x - 64;
        float* qf = sm;                      // [1024]
        float* parts = sm + 1024;            // [64][4]
        for (int i = tid; i < 1024; i += 256) qf[i] = b2f(g_XC[b * 1024 + i]);
        __syncthreads();
        int s = tid >> 2, part = tid & 3;
        const u16* row = g_ctxWin + ((size_t)(b * SRC_ + s)) * 1024 + part * 256;
        float pacc = 0.f;
        for (int j = 0; j < 256; j += 8) {
            short8 v = *(const short8*)(const void*)(row + j);
#pragma unroll
            for (int t = 0; t < 8; ++t) pacc += qf[part * 256 + j + t] * b2f(((u16*)&v)[t]);
        }
        parts[s * 4 + part] = pacc;
        __syncthreads();
        if (tid < 64) {
            float v = parts[tid * 4] + parts[tid * 4 + 1] + parts[tid * 4 + 2] + parts[tid * 4 + 3];
            float mx = v;
            for (int o = 32; o; o >>= 1) mx = fmaxf(mx, __shfl_xor(mx, o, 64));
            float e = expf(v - mx), sum = e;
            for (int o = 32; o; o >>= 1) sum += __shfl_xor(sum, o, 64);
            g_align[b * SRC_ + tid] = e / sum;
        }
    }
}

// ---------------- attn: grid 128, q-GEMM + align contraction; writes XA[dp] ------------
__global__ __launch_bounds__(256) void k_attn(int dp) {
    __shared__ float sm[64 * 17];
    const int tid = threadIdx.x, w = tid >> 6, lane = tid & 63;
    const int xcd = blockIdx.x & 7, loc = blockIdx.x >> 3;   // loc 0..15
    const int mhalf = loc & 1;
    const int n0 = (xcd * 8 + (loc >> 1)) * 16;              // N=1024 total
    f32x4 acc = {0.f, 0.f, 0.f, 0.f};
    mm1<1024>(g_XC, 1024, g_Woutb + 1024, 2048, n0, mhalf * 64 + w * 16, lane, acc);
    stage_C1(sm, w, lane, acc);
    __syncthreads();
    if (tid >= 128) return;
    int bl = tid >> 1, h8 = tid & 1;         // 64 b x 2 col-groups of 8
    int b = mhalf * 64 + bl;
    const u16* base = g_ctxW + (size_t)b * SRC_ * 1024 + n0 + h8 * 8;
    float a8[8] = {0.f, 0.f, 0.f, 0.f, 0.f, 0.f, 0.f, 0.f};
    for (int s = 0; s < SRC_; ++s) {
        float al = g_align[b * SRC_ + s];
        short8 v = *(const short8*)(const void*)(base + (size_t)s * 1024);
#pragma unroll
        for (int j = 0; j < 8; ++j) a8[j] += al * b2f(((u16*)&v)[j]);
    }
    u16 ov[8];
#pragma unroll
    for (int j = 0; j < 8; ++j) ov[j] = f2b(tanhf(a8[j] + sm[bl * 17 + h8 * 8 + j]));
    *(short8*)(void*)(g_XA[dp] + (size_t)b * KA_ + 256 + n0 + h8 * 8) = *(short8*)(void*)ov;
}

// ---------------- init / final ----------------
__global__ void k_init(const float* __restrict__ h0, const float* __restrict__ c0,
                       const float* __restrict__ z0) {
    int i = blockIdx.x * 256 + threadIdx.x;  // i < BH_
    int b = i >> 10, h = i & 1023;
    g_XA[0][(size_t)b * KA_ + 1280 + h] = f2b(h0[i]);            // h0 layer0 state
    g_XB[0][(size_t)b * KB_ + 1024 + h] = f2b(h0[BH_ + i]);      // h layer1 state
    g_XC[i] = f2b(c0[BH_ + i]);                                  // initial query c0[-1]
    g_cs0[i] = c0[i];
    g_cs1[i] = c0[BH_ + i];
    if (i < BZ_) {
        int bb = i >> 8, z = i & 255;
        g_XA[0][(size_t)bb * KA_ + z] = f2b(z0[i]);
    }
}

__global__ void k_final(float* __restrict__ out) {
    int i = blockIdx.x * 256 + threadIdx.x;  // i < BH_
    int b = i >> 10, h = i & 1023;
    float* hf = out + (size_t)3 * BKZ_;
    float* cf = hf + 2 * BH_;
    hf[i] = b2f(g_XA[0][(size_t)b * KA_ + 1280 + h]);
    hf[BH_ + i] = b2f(g_XB[0][(size_t)b * KB_ + 1024 + h]);
    cf[i] = g_cs0[i];
    cf[BH_ + i] = g_cs1[i];
}

// ---------------- prep GEMM: Out[m][n] = sum_k A[m][k]*W[n][k], 128x64 tiles ----------------
__global__ __launch_bounds__(256) void k_gemm_prep(const u16* __restrict__ A, int sA,
                                                   const u16* __restrict__ W, int sW,
                                                   u16* __restrict__ Out, int sO) {
    const int tid = threadIdx.x, w = tid >> 6, lane = tid & 63;
    const int quad = lane >> 4, l16 = lane & 15;
    const int n0 = blockIdx.x * 64;
    const int mb = blockIdx.y * 128 + w * 32;
    f32x4 acc[2][4] = {};
    const u16* pa0 = A + (size_t)(mb + l16) * sA + quad * 8;
    const u16* pa1 = pa0 + (size_t)16 * sA;
    const u16* pw = W + (size_t)(n0 + l16) * sW + quad * 8;
#pragma unroll 2
    for (int k0 = 0; k0 < 1024; k0 += 32) {
        short8 a0 = *(const short8*)(const void*)(pa0 + k0);
        short8 a1 = *(const short8*)(const void*)(pa1 + k0);
#pragma unroll
        for (int j = 0; j < 4; ++j) {
            short8 b = *(const short8*)(const void*)(pw + (size_t)j * 16 * sW + k0);
            acc[0][j] = __builtin_amdgcn_mfma_f32_16x16x32_bf16(a0, b, acc[0][j], 0, 0, 0);
            acc[1][j] = __builtin_amdgcn_mfma_f32_16x16x32_bf16(a1, b, acc[1][j], 0, 0, 0);
        }
    }
#pragma unroll
    for (int i = 0; i < 2; ++i)
#pragma unroll
        for (int j = 0; j < 4; ++j)
#pragma unroll
            for (int r = 0; r < 4; ++r)
                Out[(size_t)(mb + i * 16 + quad * 4 + r) * sO + n0 + j * 16 + l16] =
                    f2b(acc[i][j][r]);
}

extern "C" void kernel_launch(void* const* d_in, const int* in_sizes, int n_in,
                              void* d_out, int out_size, void* d_ws, size_t ws_size,
                              hipStream_t stream) {
    (void)in_sizes; (void)n_in; (void)out_size; (void)d_ws; (void)ws_size;
    const float* h0 = (const float*)d_in[0];
    const float* c0 = (const float*)d_in[1];
    const float* ctx = (const float*)d_in[2];
    const float* z0 = (const float*)d_in[3];
    const int* kvec = (const int*)d_in[4];
    const float* eps = (const float*)d_in[5];
    const float* Wih0 = (const float*)d_in[6];
    const float* Whh0 = (const float*)d_in[7];
    const float* bih0 = (const float*)d_in[8];
    const float* bhh0 = (const float*)d_in[9];
    const float* Wih1 = (const float*)d_in[10];
    const float* Whh1 = (const float*)d_in[11];
    const float* bih1 = (const float*)d_in[12];
    const float* bhh1 = (const float*)d_in[13];
    const float* Win = (const float*)d_in[14];
    const float* Wout = (const float*)d_in[15];
    const float* muW = (const float*)d_in[16];
    const float* mub = (const float*)d_in[17];
    const float* sgW = (const float*)d_in[18];
    const float* sgb = (const float*)d_in[19];
    float* out = (float*)d_out;

    dim3 blk(256);
    // ---- one-time prep ----
    prep_wc0<<<4096, blk, 0, stream>>>(Wih0, Whh0, bih0, bhh0);
    prep_wc1<<<4096, blk, 0, stream>>>(Wih1, Whh1, bih1, bhh1);
    prep_wmq<<<512, blk, 0, stream>>>(muW, mub, sgW, sgb);
    {
        u16* woutb; hipGetSymbolAddress((void**)&woutb, HIP_SYMBOL(g_Woutb));
        u16* ctxb; hipGetSymbolAddress((void**)&ctxb, HIP_SYMBOL(g_ctxb));
        u16* winT; hipGetSymbolAddress((void**)&winT, HIP_SYMBOL(g_WinT));
        u16* ctxW; hipGetSymbolAddress((void**)&ctxW, HIP_SYMBOL(g_ctxW));
        u16* ctxWin; hipGetSymbolAddress((void**)&ctxWin, HIP_SYMBOL(g_ctxWin));
        prep_copy<<<2048, blk, 0, stream>>>(Wout, woutb, 1024 * 2048);
        prep_copy<<<8192, blk, 0, stream>>>(ctx, ctxb, 8192 * 1024);
        prep_winT<<<dim3(32, 32), blk, 0, stream>>>(Win);
        // ctxW = ctx @ Wout[:, :1024]^T ; ctxWin = ctx @ Win
        k_gemm_prep<<<dim3(16, 64), blk, 0, stream>>>(ctxb, 1024, woutb, 2048, ctxW, 1024);
        k_gemm_prep<<<dim3(16, 64), blk, 0, stream>>>(ctxb, 1024, winT, 1024, ctxWin, 1024);
    }
    // ---- init state + initial attention (q = c0[-1]) ----
    k_init<<<BH_ / 256, blk, 0, stream>>>(h0, c0, z0);
    k_mq<<<192, blk, 0, stream>>>(eps, kvec, out, 0, 0, 1);   // scores only
    k_attn<<<128, blk, 0, stream>>>(0);                        // attn0 -> XA[0]

    // ---- 48 steps ----
    for (int i = 0; i < K_; ++i) {
        k_lstm_mm<0><<<512, blk, 0, stream>>>(kvec, i);
        k_lstm_mm<1><<<512, blk, 0, stream>>>(kvec, i);
        k_mq<<<192, blk, 0, stream>>>(eps, kvec, out, i, 1, (i + 1 < K_) ? 1 : 0);
        if (i + 1 < K_) k_attn<<<128, blk, 0, stream>>>((i + 1) & 1);
    }
    // K_=48 even -> final states in parity-0 buffers
    k_final<<<BH_ / 256, blk, 0, stream>>>(out);
}

// Round 7
// 4664.300 us; speedup vs baseline: 2.1188x; 1.1025x over previous
//
#include <hip/hip_runtime.h>
#include <hip/hip_bf16.h>

#define L_ 2
#define H_ 1024
#define Z_ 256
#define B_ 128
#define SRC_ 64
#define K_ 48
#define BH_ (B_ * H_)
#define BZ_ (B_ * Z_)
#define BKZ_ ((size_t)B_ * K_ * Z_)
#define KA_ 2304   // lstm0 GEMM K: z(256) | attn(1024) | h0(1024)
#define KB_ 2048   // lstm1 GEMM K: h0n(1024) | h1(1024)

typedef unsigned short u16;
typedef __attribute__((ext_vector_type(8))) short short8;
typedef __attribute__((ext_vector_type(4))) float f32x4;

// ---------------- static device workspace ----------------
__device__ __align__(16) u16 g_Wc0[4096 * KA_];     // lstm0 weights [4h+g][KA]
__device__ __align__(16) u16 g_Wc1[4096 * KB_];     // lstm1 weights
__device__ __align__(16) u16 g_Wmq[512 * 1024];     // mu/sigma rows interleaved [2z+sel][1024]
__device__ __align__(16) u16 g_Woutb[1024 * 2048];  // Wout bf16
__device__ __align__(16) u16 g_WinT[1024 * 1024];   // Win transposed bf16
__device__ __align__(16) u16 g_ctxb[8192 * 1024];   // context bf16 [B*SRC][H]
__device__ __align__(16) u16 g_ctxW[8192 * 1024];   // ctx @ Wout[:, :H]^T
__device__ __align__(16) u16 g_ctxWin[8192 * 1024]; // ctx @ Win
__device__ __align__(16) u16 g_XA[2][B_ * KA_];     // lstm0 input (dbl-buf): z|attn|h0state
__device__ __align__(16) u16 g_XB[2][B_ * KB_];     // lstm1 input: h0n|h1state
__device__ __align__(16) u16 g_XC[B_ * H_];         // h1n unfrozen (query / musig input)
__device__ float g_pb0[4096], g_pb1[4096], g_pbmq[512], g_wk0[4096];
__device__ float g_cs0[BH_], g_cs1[BH_], g_align[B_ * SRC_];

__device__ __forceinline__ float sigm(float x) { return 1.0f / (1.0f + expf(-x)); }
__device__ __forceinline__ u16 f2b(float f) {
    union { float f; unsigned u; } x; x.f = f;
    unsigned r = x.u + 0x7fffu + ((x.u >> 16) & 1u);
    return (u16)(r >> 16);
}
__device__ __forceinline__ float b2f(u16 s) {
    union { unsigned u; float f; } x; x.u = ((unsigned)s) << 16;
    return x.f;
}

// ---------------- prep kernels ----------------
__global__ void prep_wc0(const float* __restrict__ Wih, const float* __restrict__ Whh,
                         const float* __restrict__ bih, const float* __restrict__ bhh) {
    int n = blockIdx.x;                 // interleaved row: n = 4h+g
    int h = n >> 2, g = n & 3, r = g * 1024 + h;
    u16* row = g_Wc0 + (size_t)n * KA_;
    for (int j = threadIdx.x; j < KA_; j += 256) {
        float v = (j < 256) ? Wih[(size_t)r * 1281 + j]
                : (j < 1280) ? Wih[(size_t)r * 1281 + j + 1]
                             : Whh[(size_t)r * 1024 + (j - 1280)];
        row[j] = f2b(v);
    }
    if (threadIdx.x == 0) {
        g_wk0[n] = Wih[(size_t)r * 1281 + 256];
        g_pb0[n] = bih[r] + bhh[r];
    }
}

__global__ void prep_wc1(const float* __restrict__ Wih, const float* __restrict__ Whh,
                         const float* __restrict__ bih, const float* __restrict__ bhh) {
    int n = blockIdx.x;
    int h = n >> 2, g = n & 3, r = g * 1024 + h;
    u16* row = g_Wc1 + (size_t)n * KB_;
    for (int j = threadIdx.x; j < KB_; j += 256) {
        float v = (j < 1024) ? Wih[(size_t)r * 1024 + j] : Whh[(size_t)r * 1024 + (j - 1024)];
        row[j] = f2b(v);
    }
    if (threadIdx.x == 0) g_pb1[n] = bih[r] + bhh[r];
}

__global__ void prep_wmq(const float* __restrict__ muW, const float* __restrict__ mub,
                         const float* __restrict__ sgW, const float* __restrict__ sgb) {
    int n = blockIdx.x;                 // n = 2z+sel
    int z = n >> 1, sel = n & 1;
    const float* src = sel ? sgW : muW;
    u16* row = g_Wmq + (size_t)n * 1024;
    for (int j = threadIdx.x; j < 1024; j += 256) row[j] = f2b(src[(size_t)z * 1024 + j]);
    if (threadIdx.x == 0) g_pbmq[n] = sel ? sgb[z] : mub[z];
}

__global__ void prep_copy(const float* __restrict__ in, u16* __restrict__ out, int n) {
    for (int i = blockIdx.x * 256 + threadIdx.x; i < n; i += gridDim.x * 256)
        out[i] = f2b(in[i]);
}

__global__ void prep_winT(const float* __restrict__ Win) {
    __shared__ float t[32][33];
    int bx = blockIdx.x * 32, by = blockIdx.y * 32;
    int tx = threadIdx.x & 31, ty0 = threadIdx.x >> 5;
    for (int it = 0; it < 4; ++it) {
        int ty = ty0 + it * 8;
        t[ty][tx] = Win[(size_t)(by + ty) * 1024 + bx + tx];
    }
    __syncthreads();
    for (int it = 0; it < 4; ++it) {
        int ty = ty0 + it * 8;
        g_WinT[(size_t)(bx + ty) * 1024 + by + tx] = f2b(t[tx][ty]);
    }
}

// ---------------- K-split-4 MFMA quarter-loop: wave w covers K-quarter ----------------
template <int K>
__device__ __forceinline__ void mmq(const u16* __restrict__ A, int sA,
                                    const u16* __restrict__ W, int sW,
                                    int m0, int n0, int w, int lane, f32x4& acc) {
    constexpr int KQ = K / 4;
    const int quad = lane >> 4, l16 = lane & 15;
    const u16* pa = A + (size_t)(m0 + l16) * sA + w * KQ + quad * 8;
    const u16* pw = W + (size_t)(n0 + l16) * sW + w * KQ + quad * 8;
#pragma unroll 4
    for (int k0 = 0; k0 < KQ; k0 += 32) {
        short8 a = *(const short8*)(const void*)(pa + k0);
        short8 b = *(const short8*)(const void*)(pw + k0);
        acc = __builtin_amdgcn_mfma_f32_16x16x32_bf16(a, b, acc, 0, 0, 0);
    }
}

// stage one wave's partial C-tile into sm[w][16][17]
__device__ __forceinline__ void stage_q(float* sm, int w, int lane, const f32x4& acc) {
    int quad = lane >> 4, l16 = lane & 15;
#pragma unroll
    for (int r = 0; r < 4; ++r) sm[w * 272 + (quad * 4 + r) * 17 + l16] = acc[r];
}

// ---------------- LSTM GEMM+cell; grid 2048 = 8 xcd x (8 mtile x 32 ntile) -------------
template <int LAYER>
__global__ __launch_bounds__(256) void k_lstm_mm(const int* __restrict__ kvec, int step) {
    constexpr int K = (LAYER == 0) ? KA_ : KB_;
    const int p = step & 1;
    const u16* A = (LAYER == 0) ? g_XA[p] : g_XB[p];
    const u16* W = (LAYER == 0) ? g_Wc0 : g_Wc1;
    const float* pb = (LAYER == 0) ? g_pb0 : g_pb1;
    float* cs = (LAYER == 0) ? g_cs0 : g_cs1;
    const u16* stOld = (LAYER == 0) ? (g_XA[p] + 1280) : (g_XB[p] + 1024);
    u16* stNew = (LAYER == 0) ? (g_XA[1 - p] + 1280) : (g_XB[1 - p] + 1024);
    const int stStride = (LAYER == 0) ? KA_ : KB_;
    u16* hout = (LAYER == 0) ? g_XB[p] : g_XC;
    const int hoStride = (LAYER == 0) ? KB_ : 1024;

    const int tid = threadIdx.x, w = tid >> 6, lane = tid & 63;
    const int xcd = blockIdx.x & 7, loc = blockIdx.x >> 3;   // loc 0..255
    const int mt = loc & 7, nl = loc >> 3;                   // mt 0..7, nl 0..31
    const int m0 = mt * 16;
    const int n0 = (xcd * 32 + nl) * 16;                     // XCD owns fixed N-slice

    __shared__ float sm[4 * 16 * 17];
    f32x4 acc = {0.f, 0.f, 0.f, 0.f};
    mmq<K>(A, K, W, K, m0, n0, w, lane, acc);
    stage_q(sm, w, lane, acc);
    __syncthreads();

    if (tid < 64) {
        int bl = tid & 15, hl = tid >> 4;    // hl 0..3
        int b = m0 + bl;
        float g[4];
#pragma unroll
        for (int gg = 0; gg < 4; ++gg) {
            int c = 4 * hl + gg;
            float s = sm[bl * 17 + c] + sm[272 + bl * 17 + c] +
                      sm[544 + bl * 17 + c] + sm[816 + bl * 17 + c];
            g[gg] = s + pb[n0 + c];
        }
        if (LAYER == 0) {
            float kf = (float)kvec[b];
#pragma unroll
            for (int gg = 0; gg < 4; ++gg) g[gg] += kf * g_wk0[n0 + 4 * hl + gg];
        }
        int hg = (n0 >> 2) + hl;
        float cold = cs[b * 1024 + hg];
        float cn = sigm(g[1]) * cold + sigm(g[0]) * tanhf(g[2]);
        float hn = sigm(g[3]) * tanhf(cn);
        hout[(size_t)b * hoStride + hg] = f2b(hn);   // unfrozen output
        if (step < kvec[b]) {
            stNew[(size_t)b * stStride + hg] = f2b(hn);
            cs[b * 1024 + hg] = cn;
        } else {
            stNew[(size_t)b * stStride + hg] = stOld[(size_t)b * stStride + hg];
        }
    }
}

// ---------------- musig (blocks 0..255) + scores/softmax (blocks 256..383) ------------
__global__ __launch_bounds__(256) void k_mq(const float* __restrict__ eps,
                                            const int* __restrict__ kvec,
                                            float* __restrict__ out, int step,
                                            int do_mu, int do_sc) {
    __shared__ float sm[1344];
    const int tid = threadIdx.x;
    if (blockIdx.x < 256) {
        if (!do_mu) return;
        const int w = tid >> 6, lane = tid & 63;
        const int xcd = blockIdx.x & 7, loc = blockIdx.x >> 3;  // loc 0..31
        const int mt = loc & 7, nl = loc >> 3;                  // nl 0..3
        const int m0 = mt * 16;
        const int n0 = (xcd * 4 + nl) * 16;                     // N=512 total
        f32x4 acc = {0.f, 0.f, 0.f, 0.f};
        mmq<1024>(g_XC, 1024, g_Wmq, 1024, m0, n0, w, lane, acc);
        stage_q(sm, w, lane, acc);
        __syncthreads();
        if (tid < 128) {
            int bl = tid & 15, zl = tid >> 4;  // zl 0..7
            int b = m0 + bl;
            int c0 = 2 * zl, c1 = 2 * zl + 1;
            float mu = sm[bl * 17 + c0] + sm[272 + bl * 17 + c0] +
                       sm[544 + bl * 17 + c0] + sm[816 + bl * 17 + c0] + g_pbmq[n0 + c0];
            float sg = sm[bl * 17 + c1] + sm[272 + bl * 17 + c1] +
                       sm[544 + bl * 17 + c1] + sm[816 + bl * 17 + c1] + g_pbmq[n0 + c1];
            int zg = (n0 >> 1) + zl;
            float e = eps[((size_t)step * B_ + b) * Z_ + zg];
            float zn = mu + expf(sg) * e;
            g_XA[(step + 1) & 1][(size_t)b * KA_ + zg] = f2b(zn);
            bool valid = step < kvec[b];
            size_t o = ((size_t)b * K_ + step) * Z_ + zg;
            out[o] = valid ? zn : 0.f;
            out[BKZ_ + o] = valid ? mu : 0.f;
            out[2 * BKZ_ + o] = valid ? sg : 0.f;
        }
    } else {
        if (!do_sc) return;
        const int b = blockIdx.x - 256;
        float* qf = sm;                      // [1024]
        float* parts = sm + 1024;            // [64][4]
        for (int i = tid; i < 1024; i += 256) qf[i] = b2f(g_XC[b * 1024 + i]);
        __syncthreads();
        int s = tid >> 2, part = tid & 3;
        const u16* row = g_ctxWin + ((size_t)(b * SRC_ + s)) * 1024 + part * 256;
        float pacc = 0.f;
        for (int j = 0; j < 256; j += 8) {
            short8 v = *(const short8*)(const void*)(row + j);
#pragma unroll
            for (int t = 0; t < 8; ++t) pacc += qf[part * 256 + j + t] * b2f(((u16*)&v)[t]);
        }
        parts[s * 4 + part] = pacc;
        __syncthreads();
        if (tid < 64) {
            float v = parts[tid * 4] + parts[tid * 4 + 1] + parts[tid * 4 + 2] + parts[tid * 4 + 3];
            float mx = v;
            for (int o = 32; o; o >>= 1) mx = fmaxf(mx, __shfl_xor(mx, o, 64));
            float e = expf(v - mx), sum = e;
            for (int o = 32; o; o >>= 1) sum += __shfl_xor(sum, o, 64);
            g_align[b * SRC_ + tid] = e / sum;
        }
    }
}

// ---------------- attn: grid 512, q-GEMM + align contraction; writes XA[dp] -----------
__global__ __launch_bounds__(256) void k_attn(int dp) {
    __shared__ float sm[4 * 16 * 17];
    const int tid = threadIdx.x, w = tid >> 6, lane = tid & 63;
    const int xcd = blockIdx.x & 7, loc = blockIdx.x >> 3;   // loc 0..63
    const int mt = loc & 7, nl = loc >> 3;                   // nl 0..7
    const int m0 = mt * 16;
    const int n0 = (xcd * 8 + nl) * 16;                      // N=1024 total
    f32x4 acc = {0.f, 0.f, 0.f, 0.f};
    mmq<1024>(g_XC, 1024, g_Woutb + 1024, 2048, m0, n0, w, lane, acc);
    stage_q(sm, w, lane, acc);
    __syncthreads();
    // per-thread C reduce: 256 = 16 b x 16 cols (b = tid>>4 for coalesced ctxW reads)
    int bl = tid >> 4, hc = tid & 15;
    float cred = sm[bl * 17 + hc] + sm[272 + bl * 17 + hc] +
                 sm[544 + bl * 17 + hc] + sm[816 + bl * 17 + hc];
    __syncthreads();
    // stage align[16][64] into LDS (reuse sm)
    for (int i = tid; i < 16 * SRC_; i += 256)
        sm[i] = g_align[(m0 + (i >> 6)) * SRC_ + (i & 63)];
    __syncthreads();
    int b = m0 + bl;
    const u16* base = g_ctxW + ((size_t)b * SRC_) * 1024 + n0 + hc;
    float a = 0.f;
#pragma unroll 8
    for (int s = 0; s < SRC_; ++s) a += sm[bl * 64 + s] * b2f(base[(size_t)s * 1024]);
    g_XA[dp][(size_t)b * KA_ + 256 + n0 + hc] = f2b(tanhf(a + cred));
}

// ---------------- init / final ----------------
__global__ void k_init(const float* __restrict__ h0, const float* __restrict__ c0,
                       const float* __restrict__ z0) {
    int i = blockIdx.x * 256 + threadIdx.x;  // i < BH_
    int b = i >> 10, h = i & 1023;
    g_XA[0][(size_t)b * KA_ + 1280 + h] = f2b(h0[i]);            // h0 layer0 state
    g_XB[0][(size_t)b * KB_ + 1024 + h] = f2b(h0[BH_ + i]);      // h layer1 state
    g_XC[i] = f2b(c0[BH_ + i]);                                  // initial query c0[-1]
    g_cs0[i] = c0[i];
    g_cs1[i] = c0[BH_ + i];
    if (i < BZ_) {
        int bb = i >> 8, z = i & 255;
        g_XA[0][(size_t)bb * KA_ + z] = f2b(z0[i]);
    }
}

__global__ void k_final(float* __restrict__ out) {
    int i = blockIdx.x * 256 + threadIdx.x;  // i < BH_
    int b = i >> 10, h = i & 1023;
    float* hf = out + (size_t)3 * BKZ_;
    float* cf = hf + 2 * BH_;
    hf[i] = b2f(g_XA[0][(size_t)b * KA_ + 1280 + h]);
    hf[BH_ + i] = b2f(g_XB[0][(size_t)b * KB_ + 1024 + h]);
    cf[i] = g_cs0[i];
    cf[BH_ + i] = g_cs1[i];
}

// ---------------- prep GEMM: Out[m][n] = sum_k A[m][k]*W[n][k], 128x64 tiles -----------
__global__ __launch_bounds__(256) void k_gemm_prep(const u16* __restrict__ A, int sA,
                                                   const u16* __restrict__ W, int sW,
                                                   u16* __restrict__ Out, int sO) {
    const int tid = threadIdx.x, w = tid >> 6, lane = tid & 63;
    const int quad = lane >> 4, l16 = lane & 15;
    const int n0 = blockIdx.x * 64;
    const int mb = blockIdx.y * 128 + w * 32;
    f32x4 acc[2][4] = {};
    const u16* pa0 = A + (size_t)(mb + l16) * sA + quad * 8;
    const u16* pa1 = pa0 + (size_t)16 * sA;
    const u16* pw = W + (size_t)(n0 + l16) * sW + quad * 8;
#pragma unroll 2
    for (int k0 = 0; k0 < 1024; k0 += 32) {
        short8 a0 = *(const short8*)(const void*)(pa0 + k0);
        short8 a1 = *(const short8*)(const void*)(pa1 + k0);
#pragma unroll
        for (int j = 0; j < 4; ++j) {
            short8 b = *(const short8*)(const void*)(pw + (size_t)j * 16 * sW + k0);
            acc[0][j] = __builtin_amdgcn_mfma_f32_16x16x32_bf16(a0, b, acc[0][j], 0, 0, 0);
            acc[1][j] = __builtin_amdgcn_mfma_f32_16x16x32_bf16(a1, b, acc[1][j], 0, 0, 0);
        }
    }
#pragma unroll
    for (int i = 0; i < 2; ++i)
#pragma unroll
        for (int j = 0; j < 4; ++j)
#pragma unroll
            for (int r = 0; r < 4; ++r)
                Out[(size_t)(mb + i * 16 + quad * 4 + r) * sO + n0 + j * 16 + l16] =
                    f2b(acc[i][j][r]);
}

extern "C" void kernel_launch(void* const* d_in, const int* in_sizes, int n_in,
                              void* d_out, int out_size, void* d_ws, size_t ws_size,
                              hipStream_t stream) {
    (void)in_sizes; (void)n_in; (void)out_size; (void)d_ws; (void)ws_size;
    const float* h0 = (const float*)d_in[0];
    const float* c0 = (const float*)d_in[1];
    const float* ctx = (const float*)d_in[2];
    const float* z0 = (const float*)d_in[3];
    const int* kvec = (const int*)d_in[4];
    const float* eps = (const float*)d_in[5];
    const float* Wih0 = (const float*)d_in[6];
    const float* Whh0 = (const float*)d_in[7];
    const float* bih0 = (const float*)d_in[8];
    const float* bhh0 = (const float*)d_in[9];
    const float* Wih1 = (const float*)d_in[10];
    const float* Whh1 = (const float*)d_in[11];
    const float* bih1 = (const float*)d_in[12];
    const float* bhh1 = (const float*)d_in[13];
    const float* Win = (const float*)d_in[14];
    const float* Wout = (const float*)d_in[15];
    const float* muW = (const float*)d_in[16];
    const float* mub = (const float*)d_in[17];
    const float* sgW = (const float*)d_in[18];
    const float* sgb = (const float*)d_in[19];
    float* out = (float*)d_out;

    dim3 blk(256);
    // ---- one-time prep ----
    prep_wc0<<<4096, blk, 0, stream>>>(Wih0, Whh0, bih0, bhh0);
    prep_wc1<<<4096, blk, 0, stream>>>(Wih1, Whh1, bih1, bhh1);
    prep_wmq<<<512, blk, 0, stream>>>(muW, mub, sgW, sgb);
    {
        u16* woutb; hipGetSymbolAddress((void**)&woutb, HIP_SYMBOL(g_Woutb));
        u16* ctxb; hipGetSymbolAddress((void**)&ctxb, HIP_SYMBOL(g_ctxb));
        u16* winT; hipGetSymbolAddress((void**)&winT, HIP_SYMBOL(g_WinT));
        u16* ctxW; hipGetSymbolAddress((void**)&ctxW, HIP_SYMBOL(g_ctxW));
        u16* ctxWin; hipGetSymbolAddress((void**)&ctxWin, HIP_SYMBOL(g_ctxWin));
        prep_copy<<<2048, blk, 0, stream>>>(Wout, woutb, 1024 * 2048);
        prep_copy<<<8192, blk, 0, stream>>>(ctx, ctxb, 8192 * 1024);
        prep_winT<<<dim3(32, 32), blk, 0, stream>>>(Win);
        // ctxW = ctx @ Wout[:, :1024]^T ; ctxWin = ctx @ Win
        k_gemm_prep<<<dim3(16, 64), blk, 0, stream>>>(ctxb, 1024, woutb, 2048, ctxW, 1024);
        k_gemm_prep<<<dim3(16, 64), blk, 0, stream>>>(ctxb, 1024, winT, 1024, ctxWin, 1024);
    }
    // ---- init state + initial attention (q = c0[-1]) ----
    k_init<<<BH_ / 256, blk, 0, stream>>>(h0, c0, z0);
    k_mq<<<384, blk, 0, stream>>>(eps, kvec, out, 0, 0, 1);   // scores only
    k_attn<<<512, blk, 0, stream>>>(0);                        // attn0 -> XA[0]

    // ---- 48 steps ----
    for (int i = 0; i < K_; ++i) {
        k_lstm_mm<0><<<2048, blk, 0, stream>>>(kvec, i);
        k_lstm_mm<1><<<2048, blk, 0, stream>>>(kvec, i);
        k_mq<<<384, blk, 0, stream>>>(eps, kvec, out, i, 1, (i + 1 < K_) ? 1 : 0);
        if (i + 1 < K_) k_attn<<<512, blk, 0, stream>>>((i + 1) & 1);
    }
    // K_=48 even -> final states in parity-0 buffers
    k_final<<<BH_ / 256, blk, 0, stream>>>(out);
}